// Round 21
// baseline (441.090 us; speedup 1.0000x reference)
//
#include <hip/hip_runtime.h>

#define M_NODES 100000
#define N_EDGES_C 800000
#define IN_DIM_C 128
#define HID_C 256
#define N_GRAPHS_C 256
#define BN_EPS_C 1e-5f

typedef __attribute__((ext_vector_type(8))) short short8v;
typedef __attribute__((ext_vector_type(4))) float floatx4;

__device__ __forceinline__ unsigned short bf16_rne(float f) {
    union { float f; unsigned u; } x; x.f = f;
    unsigned r = x.u + 0x7FFF + ((x.u >> 16) & 1);
    return (unsigned short)(r >> 16);
}
__device__ __forceinline__ float bf16_to_f(unsigned short h) {
    union { unsigned u; float f; } x; x.u = ((unsigned)h) << 16;
    return x.f;
}
__device__ __forceinline__ float bf16lo_f(unsigned u) {
    union { unsigned u; float f; } x; x.u = u << 16;
    return x.f;
}
__device__ __forceinline__ float bf16hi_f(unsigned u) {
    union { unsigned u; float f; } x; x.u = u & 0xffff0000u;
    return x.f;
}

// fragment-major W offset
template <int K>
__device__ __forceinline__ long long woff(int c, int k) {
    return ((long long)((k >> 5) * 16 + (c >> 4))) * 512 + ((k >> 3) & 3) * 128 +
           (c & 15) * 8 + (k & 7);
}

// ---------------- small helpers ----------------
__global__ void zero_f(float* __restrict__ p, int n) {
    int i = blockIdx.x * blockDim.x + threadIdx.x;
    if (i < n) p[i] = 0.f;
}
__global__ void zero_i(int* __restrict__ p, int n) {
    int i = blockIdx.x * blockDim.x + threadIdx.x;
    if (i < n) p[i] = 0;
}
__global__ void copy_i(const int* __restrict__ s, int* __restrict__ d, int n) {
    int i = blockIdx.x * blockDim.x + threadIdx.x;
    if (i < n) d[i] = s[i];
}
__global__ void f2b(const float4* __restrict__ in, ushort4* __restrict__ out, int n4) {
    int i = blockIdx.x * blockDim.x + threadIdx.x;
    if (i >= n4) return;
    float4 v = in[i];
    ushort4 o;
    o.x = bf16_rne(v.x); o.y = bf16_rne(v.y); o.z = bf16_rne(v.z); o.w = bf16_rne(v.w);
    out[i] = o;
}

// P = bf16(relu(h*sc+sh)) elementwise over [M][256]
__global__ void bnrelu(const unsigned short* __restrict__ in, const float* __restrict__ ss,
                       unsigned short* __restrict__ outP, int n8) {
    int i = blockIdx.x * blockDim.x + threadIdx.x;
    if (i >= n8) return;
    int f = (i & 31) << 3;
    uint4 u = *(const uint4*)(in + (long long)i * 8);
    float t[8] = {bf16lo_f(u.x), bf16hi_f(u.x), bf16lo_f(u.y), bf16hi_f(u.y),
                  bf16lo_f(u.z), bf16hi_f(u.z), bf16lo_f(u.w), bf16hi_f(u.w)};
    unsigned short o[8];
#pragma unroll
    for (int j = 0; j < 8; ++j)
        o[j] = bf16_rne(fmaxf(fmaf(t[j], ss[f + j], ss[HID_C + f + j]), 0.f));
    uint4 v;
    v.x = (unsigned)o[0] | ((unsigned)o[1] << 16);
    v.y = (unsigned)o[2] | ((unsigned)o[3] << 16);
    v.z = (unsigned)o[4] | ((unsigned)o[5] << 16);
    v.w = (unsigned)o[6] | ((unsigned)o[7] << 16);
    *(uint4*)(outP + (long long)i * 8) = v;
}

// ---------------- W -> fragment-major, single-plane (rounded bf16) ----------------
template <int K>
__global__ void wpack(const float* __restrict__ W, unsigned short* __restrict__ hi) {
    int t = blockIdx.x * blockDim.x + threadIdx.x;
    if (t >= K * HID_C) return;
    int k = t % K, c = t / K;
    hi[woff<K>(c, k)] = bf16_rne(W[(long long)k * HID_C + c]);
}

// ---------------- CSR build ----------------
__global__ void csr_count(const int* __restrict__ dst, int* __restrict__ counts) {
    int e = blockIdx.x * blockDim.x + threadIdx.x;
    if (e < N_EDGES_C) atomicAdd(&counts[dst[e]], 1);
}

__global__ __launch_bounds__(256) void block_scan(const int* __restrict__ counts,
                                                  int* __restrict__ excl,
                                                  int* __restrict__ partials) {
    __shared__ int sm[256];
    int i = blockIdx.x * 256 + threadIdx.x;
    int v = (i < M_NODES) ? counts[i] : 0;
    sm[threadIdx.x] = v;
    __syncthreads();
    for (int off = 1; off < 256; off <<= 1) {
        int add = (threadIdx.x >= off) ? sm[threadIdx.x - off] : 0;
        __syncthreads();
        sm[threadIdx.x] += add;
        __syncthreads();
    }
    if (i <= M_NODES) excl[i] = sm[threadIdx.x] - v;
    if (threadIdx.x == 255) partials[blockIdx.x] = sm[255];
}

__global__ __launch_bounds__(512) void scan_partials(int* __restrict__ partials, int nb) {
    __shared__ int sm[512];
    int t = threadIdx.x;
    int v = (t < nb) ? partials[t] : 0;
    sm[t] = v;
    __syncthreads();
    for (int off = 1; off < 512; off <<= 1) {
        int add = (t >= off) ? sm[t - off] : 0;
        __syncthreads();
        sm[t] += add;
        __syncthreads();
    }
    if (t < nb) partials[t] = sm[t] - v;
}

__global__ void add_offsets(int* __restrict__ rowptr, const int* __restrict__ partials) {
    int i = blockIdx.x * 256 + threadIdx.x;
    if (i <= M_NODES) rowptr[i] += partials[blockIdx.x];
}

__global__ void csr_fill(const int* __restrict__ src, const int* __restrict__ dst,
                         int* __restrict__ fillpos, int* __restrict__ csr_src) {
    int e = blockIdx.x * blockDim.x + threadIdx.x;
    if (e >= N_EDGES_C) return;
    int pos = atomicAdd(&fillpos[dst[e]], 1);
    csr_src[pos] = src[e];
}

// ---------------- paired gather: 2 nodes/thread for edge-loop ILP ----------------
// block = 256 threads = 16 feat-chunks x 16 node-slots; handles 32 nodes (n, n+16).
// Per iteration: 2*CH independent clamped loads (both nodes), predicated accumulate.
// A layout: off(row,k) = ((row>>4)*(K/8) + (k>>3))*128 + (row&15)*8 + (k&7)
template <int K>
__global__ __launch_bounds__(256) void gather_pair(const unsigned short* __restrict__ h,
                                                   const int* __restrict__ rowptr,
                                                   const int* __restrict__ csr_src,
                                                   unsigned short* __restrict__ outA) {
    constexpr int CH = K / 128;
    const int nlow = threadIdx.x & 15;
    const int q = threadIdx.x >> 4;
    const int n0 = blockIdx.x * 32 + nlow;
    const int n1 = n0 + 16;
    const int nc0 = n0 < M_NODES ? n0 : M_NODES - 1;
    const int nc1 = n1 < M_NODES ? n1 : M_NODES - 1;

    float a0[CH][8], a1[CH][8];
    // self terms
#pragma unroll
    for (int cc = 0; cc < CH; ++cc) {
        uint4 u = *(const uint4*)(h + (long long)nc0 * K + cc * 128 + q * 8);
        a0[cc][0] = bf16lo_f(u.x); a0[cc][1] = bf16hi_f(u.x);
        a0[cc][2] = bf16lo_f(u.y); a0[cc][3] = bf16hi_f(u.y);
        a0[cc][4] = bf16lo_f(u.z); a0[cc][5] = bf16hi_f(u.z);
        a0[cc][6] = bf16lo_f(u.w); a0[cc][7] = bf16hi_f(u.w);
        uint4 v = *(const uint4*)(h + (long long)nc1 * K + cc * 128 + q * 8);
        a1[cc][0] = bf16lo_f(v.x); a1[cc][1] = bf16hi_f(v.x);
        a1[cc][2] = bf16lo_f(v.y); a1[cc][3] = bf16hi_f(v.y);
        a1[cc][4] = bf16lo_f(v.z); a1[cc][5] = bf16hi_f(v.z);
        a1[cc][6] = bf16lo_f(v.w); a1[cc][7] = bf16hi_f(v.w);
    }

    const int beg0 = rowptr[nc0], d0 = rowptr[nc0 + 1] - beg0;
    const int beg1 = rowptr[nc1], d1 = rowptr[nc1 + 1] - beg1;
    const int imax = d0 > d1 ? d0 : d1;

    for (int i = 0; i < imax; ++i) {
        int i0 = i < d0 ? i : (d0 > 0 ? d0 - 1 : 0);
        int i1 = i < d1 ? i : (d1 > 0 ? d1 - 1 : 0);
        long long s0 = csr_src[beg0 + i0];
        long long s1 = csr_src[beg1 + i1];
#pragma unroll
        for (int cc = 0; cc < CH; ++cc) {
            uint4 u = *(const uint4*)(h + s0 * K + cc * 128 + q * 8);
            uint4 v = *(const uint4*)(h + s1 * K + cc * 128 + q * 8);
            if (i < d0) {
                a0[cc][0] += bf16lo_f(u.x); a0[cc][1] += bf16hi_f(u.x);
                a0[cc][2] += bf16lo_f(u.y); a0[cc][3] += bf16hi_f(u.y);
                a0[cc][4] += bf16lo_f(u.z); a0[cc][5] += bf16hi_f(u.z);
                a0[cc][6] += bf16lo_f(u.w); a0[cc][7] += bf16hi_f(u.w);
            }
            if (i < d1) {
                a1[cc][0] += bf16lo_f(v.x); a1[cc][1] += bf16hi_f(v.x);
                a1[cc][2] += bf16lo_f(v.y); a1[cc][3] += bf16hi_f(v.y);
                a1[cc][4] += bf16lo_f(v.z); a1[cc][5] += bf16hi_f(v.z);
                a1[cc][6] += bf16lo_f(v.w); a1[cc][7] += bf16hi_f(v.w);
            }
        }
    }

    if (n0 < M_NODES) {
#pragma unroll
        for (int cc = 0; cc < CH; ++cc) {
            uint4 o;
            o.x = (unsigned)bf16_rne(a0[cc][0]) | ((unsigned)bf16_rne(a0[cc][1]) << 16);
            o.y = (unsigned)bf16_rne(a0[cc][2]) | ((unsigned)bf16_rne(a0[cc][3]) << 16);
            o.z = (unsigned)bf16_rne(a0[cc][4]) | ((unsigned)bf16_rne(a0[cc][5]) << 16);
            o.w = (unsigned)bf16_rne(a0[cc][6]) | ((unsigned)bf16_rne(a0[cc][7]) << 16);
            long long off = ((long long)(n0 >> 4) * (K / 8) + cc * 16 + q) * 128 + (n0 & 15) * 8;
            *(uint4*)(outA + off) = o;
        }
    }
    if (n1 < M_NODES) {
#pragma unroll
        for (int cc = 0; cc < CH; ++cc) {
            uint4 o;
            o.x = (unsigned)bf16_rne(a1[cc][0]) | ((unsigned)bf16_rne(a1[cc][1]) << 16);
            o.y = (unsigned)bf16_rne(a1[cc][2]) | ((unsigned)bf16_rne(a1[cc][3]) << 16);
            o.z = (unsigned)bf16_rne(a1[cc][4]) | ((unsigned)bf16_rne(a1[cc][5]) << 16);
            o.w = (unsigned)bf16_rne(a1[cc][6]) | ((unsigned)bf16_rne(a1[cc][7]) << 16);
            long long off = ((long long)(n1 >> 4) * (K / 8) + cc * 16 + q) * 128 + (n1 & 15) * 8;
            *(uint4*)(outA + off) = o;
        }
    }
}

// ---------------- fused MLP, 512 threads / 8 waves, single-plane W ----------------
template <int K>
__global__ __launch_bounds__(512, 6) void fused_mlp(const unsigned short* __restrict__ A,
                                                    const unsigned short* __restrict__ W1,
                                                    const float* __restrict__ b1,
                                                    const unsigned short* __restrict__ W2,
                                                    const float* __restrict__ b2,
                                                    unsigned short* __restrict__ outH,
                                                    int M, float* __restrict__ bnsums) {
    __shared__ char lds_raw[32768];  // H tile: 64 rows x 256 cols bf16, XOR-swizzled

    const int tid = threadIdx.x;
    const int lane = tid & 63;
    const int wv = tid >> 6;
    const int gm = blockIdx.x * 64;
    const int l15 = lane & 15;
    const int kgrp = lane >> 4;
    const int rgrp = kgrp * 4;
    const int laneoff = kgrp * 128 + l15 * 8;

    floatx4 acc[4][2];
#pragma unroll
    for (int i = 0; i < 4; ++i)
#pragma unroll
        for (int j = 0; j < 2; ++j) acc[i][j] = (floatx4){0.f, 0.f, 0.f, 0.f};

    // ---------- stage 1: H = relu(A@W1+b1), A from global (frag-major) ----------
    long long aseg[4];
#pragma unroll
    for (int i = 0; i < 4; ++i) {
        int rt = (gm >> 4) + i;
        if (rt > M / 16 - 1) rt = M / 16 - 1;
        aseg[i] = (long long)rt * (K / 8) * 128;
    }

#pragma unroll
    for (int k0 = 0; k0 < K; k0 += 32) {
        short8v af[4], bh[2];
#pragma unroll
        for (int i = 0; i < 4; ++i)
            af[i] = *(const short8v*)(A + aseg[i] + k0 * 16 + laneoff);
#pragma unroll
        for (int j = 0; j < 2; ++j) {
            long long wb = (long long)((k0 >> 5) * 16 + wv * 2 + j) * 512 + laneoff;
            bh[j] = *(const short8v*)(W1 + wb);
        }
#pragma unroll
        for (int i = 0; i < 4; ++i)
#pragma unroll
            for (int j = 0; j < 2; ++j)
                acc[i][j] = __builtin_amdgcn_mfma_f32_16x16x32_bf16(af[i], bh[j], acc[i][j], 0, 0, 0);
    }

    // write relu'd bf16 H tile into swizzled LDS [64][256]
#pragma unroll
    for (int j = 0; j < 2; ++j) {
        int col = wv * 32 + j * 16 + l15;
        float bb = b1[col];
#pragma unroll
        for (int i = 0; i < 4; ++i) {
            int lrow = i * 16 + rgrp;
#pragma unroll
            for (int r = 0; r < 4; ++r) {
                int row = lrow + r;
                float v = fmaxf(acc[i][j][r] + bb, 0.f);
                int bo = (row * 512 + col * 2) ^ ((row & 7) << 4);
                *(unsigned short*)(lds_raw + bo) = bf16_rne(v);
            }
        }
    }
    __syncthreads();

    // ---------- stage 2: out = H@W2+b2, W2 single-plane ----------
#pragma unroll
    for (int i = 0; i < 4; ++i)
#pragma unroll
        for (int j = 0; j < 2; ++j) acc[i][j] = (floatx4){0.f, 0.f, 0.f, 0.f};

#pragma unroll
    for (int k0 = 0; k0 < HID_C; k0 += 32) {
        short8v af[4], bh[2];
#pragma unroll
        for (int i = 0; i < 4; ++i) {
            int row = i * 16 + l15;
            int bo = (row * 512 + (k0 + kgrp * 8) * 2) ^ ((row & 7) << 4);
            af[i] = *(const short8v*)(lds_raw + bo);
        }
#pragma unroll
        for (int j = 0; j < 2; ++j) {
            long long wb = (long long)((k0 >> 5) * 16 + wv * 2 + j) * 512 + laneoff;
            bh[j] = *(const short8v*)(W2 + wb);
        }
#pragma unroll
        for (int i = 0; i < 4; ++i)
#pragma unroll
            for (int j = 0; j < 2; ++j)
                acc[i][j] = __builtin_amdgcn_mfma_f32_16x16x32_bf16(af[i], bh[j], acc[i][j], 0, 0, 0);
    }

    // fused BN column sums (exact fp32 from accumulators)
#pragma unroll
    for (int j = 0; j < 2; ++j) {
        int col = wv * 32 + j * 16 + l15;
        float bb = b2[col];
        float s1 = 0.f, s2 = 0.f;
#pragma unroll
        for (int i = 0; i < 4; ++i) {
            int rowb = gm + i * 16 + rgrp;
#pragma unroll
            for (int r = 0; r < 4; ++r) {
                if (rowb + r < M) {
                    float v = acc[i][j][r] + bb;
                    s1 += v; s2 += v * v;
                }
            }
        }
        s1 += __shfl_xor(s1, 16); s1 += __shfl_xor(s1, 32);
        s2 += __shfl_xor(s2, 16); s2 += __shfl_xor(s2, 32);
        if ((lane >> 4) == 0) {
            atomicAdd(&bnsums[col], s1);
            atomicAdd(&bnsums[HID_C + col], s2);
        }
    }

    // coalesced bf16 epilogue via LDS (reuse lds_raw), 2 col-half phases
    unsigned short* stg = (unsigned short*)lds_raw;  // [64][132]
#pragma unroll
    for (int p = 0; p < 2; ++p) {
        __syncthreads();
        if ((wv >> 2) == p) {
#pragma unroll
            for (int j = 0; j < 2; ++j) {
                int col = wv * 32 + j * 16 + l15;
                int lcol = (wv & 3) * 32 + j * 16 + l15;
                float bb = b2[col];
#pragma unroll
                for (int i = 0; i < 4; ++i) {
                    int lrow = i * 16 + rgrp;
#pragma unroll
                    for (int r = 0; r < 4; ++r)
                        stg[(lrow + r) * 132 + lcol] = bf16_rne(acc[i][j][r] + bb);
                }
            }
        }
        __syncthreads();
#pragma unroll
        for (int it = 0; it < 4; ++it) {
            int idx = it * 512 + tid;
            int row = idx >> 5;
            int c4 = idx & 31;
            int grow = gm + row;
            if (grow < M)
                *(ushort4*)(outH + (long long)grow * HID_C + p * 128 + c4 * 4) =
                    *(const ushort4*)&stg[row * 132 + c4 * 4];
        }
    }
}

// ---------------- BatchNorm finalize ----------------
__global__ void bn_finalize(const float* __restrict__ sums, const float* __restrict__ gamma,
                            const float* __restrict__ beta, float* __restrict__ ss) {
    int f = threadIdx.x;
    float mean = sums[f] * (1.0f / M_NODES);
    float var = sums[HID_C + f] * (1.0f / M_NODES) - mean * mean;
    float sc = gamma[f] * rsqrtf(var + BN_EPS_C);
    ss[f] = sc;
    ss[HID_C + f] = beta[f] - mean * sc;
}

// ---------------- pooling (bf16 in, fused BN+relu) ----------------
#define POOL_BLOCKS 4096
#define POOL_RPB 25
__global__ void pool_bn(const unsigned short* __restrict__ h, const float* __restrict__ ss,
                        const int* __restrict__ batch, float* __restrict__ sums, int M) {
    int f = threadIdx.x;
    float sc = ss[f], sh = ss[HID_C + f];
    int r0 = blockIdx.x * POOL_RPB;
    if (r0 >= M) return;
    int r1 = r0 + POOL_RPB;
    if (r1 > M) r1 = M;
    int cur = batch[r0];
    float acc = 0.f;
    for (int r = r0; r < r1; ++r) {
        int g = batch[r];
        if (g != cur) {
            atomicAdd(&sums[(long long)cur * HID_C + f], acc);
            acc = 0.f;
            cur = g;
        }
        float v = bf16_to_f(h[(long long)r * HID_C + f]);
        acc += fmaxf(fmaf(v, sc, sh), 0.f);
    }
    atomicAdd(&sums[(long long)cur * HID_C + f], acc);
}

__device__ __forceinline__ int lower_bound_i(const int* a, int n, int v) {
    int lo = 0, hi = n;
    while (lo < hi) {
        int mid = (lo + hi) >> 1;
        if (a[mid] < v) lo = mid + 1;
        else hi = mid;
    }
    return lo;
}

__global__ void pool_finalize(const float* __restrict__ sums, const int* __restrict__ batch,
                              float* __restrict__ out) {
    int g = blockIdx.x, f = threadIdx.x;
    int lb = lower_bound_i(batch, M_NODES, g);
    int ub = lower_bound_i(batch, M_NODES, g + 1);
    float cnt = (float)(ub - lb);
    out[(long long)g * HID_C + f] = sums[(long long)g * HID_C + f] / fmaxf(cnt, 1.0f);
}

// ---------------- launch ----------------
extern "C" void kernel_launch(void* const* d_in, const int* in_sizes, int n_in,
                              void* d_out, int out_size, void* d_ws, size_t ws_size,
                              hipStream_t stream) {
    const float* x = (const float*)d_in[0];
    const int* ei = (const int*)d_in[1];
    const int* esrc = ei;
    const int* edst = ei + N_EDGES_C;
    const int* batch = (const int*)d_in[2];
    const float* W1_0 = (const float*)d_in[3];
    const float* b1_0 = (const float*)d_in[4];
    const float* W2_0 = (const float*)d_in[5];
    const float* b2_0 = (const float*)d_in[6];
    const float* g0 = (const float*)d_in[7];
    const float* be0 = (const float*)d_in[8];
    const float* W1_1 = (const float*)d_in[9];
    const float* b1_1 = (const float*)d_in[10];
    const float* W2_1 = (const float*)d_in[11];
    const float* b2_1 = (const float*)d_in[12];
    const float* g1 = (const float*)d_in[13];
    const float* be1 = (const float*)d_in[14];
    float* out = (float*)d_out;

    const long long NF = (long long)M_NODES * HID_C;
    const long long NI = (long long)M_NODES * IN_DIM_C;
    unsigned short* U = (unsigned short*)d_ws;
    unsigned short* X16 = U;           // NI  (bf16 x)          [dead after L0 gather]
    unsigned short* A0 = U + NI;       // NI  (frag-major)      [dead after L0 mlp]
    unsigned short* P1 = U;            // NF  (aliases X16+A0; written by bnrelu)
    unsigned short* Hb0 = U + 2 * NI;  // NF  (pre-BN out L0)
    unsigned short* A1 = Hb0 + NF;     // NF  (frag-major)
    unsigned short* Hb1 = A1 + NF;     // NF  (pre-BN out L1)
    float* fbase = (float*)(Hb1 + NF);
    float* bns = fbase;
    float* ss0 = bns + 2 * HID_C;
    float* ss1 = ss0 + 2 * HID_C;
    float* psum = ss1 + 2 * HID_C;
    int* counts = (int*)(psum + N_GRAPHS_C * HID_C);
    int* partials = counts + 100352;
    int* rowptr = partials + 512;
    int* csr_src = rowptr + 100004;
    unsigned short* wp = (unsigned short*)(csr_src + N_EDGES_C);
    unsigned short* w1A = wp;                      // 128*256 single-plane
    unsigned short* w2B = w1A + IN_DIM_C * HID_C;  // 256*256 single-plane
    unsigned short* w1C = w2B + HID_C * HID_C;
    unsigned short* w2D = w1C + HID_C * HID_C;

    dim3 blk(256);
    dim3 fgrid((M_NODES + 63) / 64);
    dim3 pgrid((M_NODES + 31) / 32);

    // ---- W packs (fragment-major, single-plane) ----
    wpack<IN_DIM_C><<<(IN_DIM_C * HID_C + 255) / 256, blk, 0, stream>>>(W1_0, w1A);
    wpack<HID_C><<<(HID_C * HID_C + 255) / 256, blk, 0, stream>>>(W2_0, w2B);
    wpack<HID_C><<<(HID_C * HID_C + 255) / 256, blk, 0, stream>>>(W1_1, w1C);
    wpack<HID_C><<<(HID_C * HID_C + 255) / 256, blk, 0, stream>>>(W2_1, w2D);

    // ---- CSR build ----
    zero_i<<<(M_NODES + 255) / 256, blk, 0, stream>>>(counts, M_NODES);
    csr_count<<<(N_EDGES_C + 255) / 256, blk, 0, stream>>>(edst, counts);
    block_scan<<<392, blk, 0, stream>>>(counts, rowptr, partials);
    scan_partials<<<1, 512, 0, stream>>>(partials, 392);
    add_offsets<<<392, blk, 0, stream>>>(rowptr, partials);
    copy_i<<<(M_NODES + 255) / 256, blk, 0, stream>>>(rowptr, counts, M_NODES);
    csr_fill<<<(N_EDGES_C + 255) / 256, blk, 0, stream>>>(esrc, edst, counts, csr_src);

    // ---- x -> bf16 ----
    f2b<<<(int)((NI / 4 + 255) / 256), blk, 0, stream>>>((const float4*)x, (ushort4*)X16,
                                                         (int)(NI / 4));

    // ---- Layer 0 ----
    gather_pair<IN_DIM_C><<<pgrid, blk, 0, stream>>>(X16, rowptr, csr_src, A0);
    zero_f<<<2, blk, 0, stream>>>(bns, 2 * HID_C);
    fused_mlp<IN_DIM_C><<<fgrid, dim3(512), 0, stream>>>(A0, w1A, b1_0, w2B, b2_0,
                                                         Hb0, M_NODES, bns);
    bn_finalize<<<1, blk, 0, stream>>>(bns, g0, be0, ss0);

    // ---- P1 = relu(BN(Hb0))  (aliases dead X16+A0 region) ----
    bnrelu<<<(int)((NF / 8 + 255) / 256), blk, 0, stream>>>(Hb0, ss0, P1, (int)(NF / 8));

    // ---- Layer 1 ----
    gather_pair<HID_C><<<pgrid, blk, 0, stream>>>(P1, rowptr, csr_src, A1);
    zero_f<<<2, blk, 0, stream>>>(bns, 2 * HID_C);
    fused_mlp<HID_C><<<fgrid, dim3(512), 0, stream>>>(A1, w1C, b1_1, w2D, b2_1,
                                                      Hb1, M_NODES, bns);
    bn_finalize<<<1, blk, 0, stream>>>(bns, g1, be1, ss1);

    // ---- Pool (fused BN+relu) ----
    zero_f<<<(N_GRAPHS_C * HID_C + 255) / 256, blk, 0, stream>>>(psum, N_GRAPHS_C * HID_C);
    pool_bn<<<POOL_BLOCKS, blk, 0, stream>>>(Hb1, ss1, batch, psum, M_NODES);
    pool_finalize<<<256, blk, 0, stream>>>(psum, batch, out);
}

// Round 22
// 412.692 us; speedup vs baseline: 1.0688x; 1.0688x over previous
//
#include <hip/hip_runtime.h>

#define M_NODES 100000
#define N_EDGES_C 800000
#define IN_DIM_C 128
#define HID_C 256
#define N_GRAPHS_C 256
#define BN_EPS_C 1e-5f

typedef __attribute__((ext_vector_type(8))) short short8v;
typedef __attribute__((ext_vector_type(4))) float floatx4;

__device__ __forceinline__ unsigned short bf16_rne(float f) {
    union { float f; unsigned u; } x; x.f = f;
    unsigned r = x.u + 0x7FFF + ((x.u >> 16) & 1);
    return (unsigned short)(r >> 16);
}
__device__ __forceinline__ float bf16_to_f(unsigned short h) {
    union { unsigned u; float f; } x; x.u = ((unsigned)h) << 16;
    return x.f;
}
__device__ __forceinline__ float bf16lo_f(unsigned u) {
    union { unsigned u; float f; } x; x.u = u << 16;
    return x.f;
}
__device__ __forceinline__ float bf16hi_f(unsigned u) {
    union { unsigned u; float f; } x; x.u = u & 0xffff0000u;
    return x.f;
}

// fragment-major W offset
template <int K>
__device__ __forceinline__ long long woff(int c, int k) {
    return ((long long)((k >> 5) * 16 + (c >> 4))) * 512 + ((k >> 3) & 3) * 128 +
           (c & 15) * 8 + (k & 7);
}

// ---------------- small helpers ----------------
__global__ void zero_f(float* __restrict__ p, int n) {
    int i = blockIdx.x * blockDim.x + threadIdx.x;
    if (i < n) p[i] = 0.f;
}
__global__ void zero_i(int* __restrict__ p, int n) {
    int i = blockIdx.x * blockDim.x + threadIdx.x;
    if (i < n) p[i] = 0;
}
__global__ void copy_i(const int* __restrict__ s, int* __restrict__ d, int n) {
    int i = blockIdx.x * blockDim.x + threadIdx.x;
    if (i < n) d[i] = s[i];
}
__global__ void f2b(const float4* __restrict__ in, ushort4* __restrict__ out, int n4) {
    int i = blockIdx.x * blockDim.x + threadIdx.x;
    if (i >= n4) return;
    float4 v = in[i];
    ushort4 o;
    o.x = bf16_rne(v.x); o.y = bf16_rne(v.y); o.z = bf16_rne(v.z); o.w = bf16_rne(v.w);
    out[i] = o;
}

// P = bf16(relu(h*sc+sh)) elementwise over [M][256]
__global__ void bnrelu(const unsigned short* __restrict__ in, const float* __restrict__ ss,
                       unsigned short* __restrict__ outP, int n8) {
    int i = blockIdx.x * blockDim.x + threadIdx.x;
    if (i >= n8) return;
    int f = (i & 31) << 3;
    uint4 u = *(const uint4*)(in + (long long)i * 8);
    float t[8] = {bf16lo_f(u.x), bf16hi_f(u.x), bf16lo_f(u.y), bf16hi_f(u.y),
                  bf16lo_f(u.z), bf16hi_f(u.z), bf16lo_f(u.w), bf16hi_f(u.w)};
    unsigned short o[8];
#pragma unroll
    for (int j = 0; j < 8; ++j)
        o[j] = bf16_rne(fmaxf(fmaf(t[j], ss[f + j], ss[HID_C + f + j]), 0.f));
    uint4 v;
    v.x = (unsigned)o[0] | ((unsigned)o[1] << 16);
    v.y = (unsigned)o[2] | ((unsigned)o[3] << 16);
    v.z = (unsigned)o[4] | ((unsigned)o[5] << 16);
    v.w = (unsigned)o[6] | ((unsigned)o[7] << 16);
    *(uint4*)(outP + (long long)i * 8) = v;
}

// ---------------- W -> fragment-major, single-plane (rounded bf16) ----------------
template <int K>
__global__ void wpack(const float* __restrict__ W, unsigned short* __restrict__ hi) {
    int t = blockIdx.x * blockDim.x + threadIdx.x;
    if (t >= K * HID_C) return;
    int k = t % K, c = t / K;
    hi[woff<K>(c, k)] = bf16_rne(W[(long long)k * HID_C + c]);
}

// ---------------- CSR build ----------------
__global__ void csr_count(const int* __restrict__ dst, int* __restrict__ counts) {
    int e = blockIdx.x * blockDim.x + threadIdx.x;
    if (e < N_EDGES_C) atomicAdd(&counts[dst[e]], 1);
}

__global__ __launch_bounds__(256) void block_scan(const int* __restrict__ counts,
                                                  int* __restrict__ excl,
                                                  int* __restrict__ partials) {
    __shared__ int sm[256];
    int i = blockIdx.x * 256 + threadIdx.x;
    int v = (i < M_NODES) ? counts[i] : 0;
    sm[threadIdx.x] = v;
    __syncthreads();
    for (int off = 1; off < 256; off <<= 1) {
        int add = (threadIdx.x >= off) ? sm[threadIdx.x - off] : 0;
        __syncthreads();
        sm[threadIdx.x] += add;
        __syncthreads();
    }
    if (i <= M_NODES) excl[i] = sm[threadIdx.x] - v;
    if (threadIdx.x == 255) partials[blockIdx.x] = sm[255];
}

__global__ __launch_bounds__(512) void scan_partials(int* __restrict__ partials, int nb) {
    __shared__ int sm[512];
    int t = threadIdx.x;
    int v = (t < nb) ? partials[t] : 0;
    sm[t] = v;
    __syncthreads();
    for (int off = 1; off < 512; off <<= 1) {
        int add = (t >= off) ? sm[t - off] : 0;
        __syncthreads();
        sm[t] += add;
        __syncthreads();
    }
    if (t < nb) partials[t] = sm[t] - v;
}

__global__ void add_offsets(int* __restrict__ rowptr, const int* __restrict__ partials) {
    int i = blockIdx.x * 256 + threadIdx.x;
    if (i <= M_NODES) rowptr[i] += partials[blockIdx.x];
}

__global__ void csr_fill(const int* __restrict__ src, const int* __restrict__ dst,
                         int* __restrict__ fillpos, int* __restrict__ csr_src) {
    int e = blockIdx.x * blockDim.x + threadIdx.x;
    if (e >= N_EDGES_C) return;
    int pos = atomicAdd(&fillpos[dst[e]], 1);
    csr_src[pos] = src[e];
}

// ---------------- gather helpers ----------------
template <int CH>
__device__ __forceinline__ void load_row(const unsigned short* __restrict__ h,
                                         long long s, int q, unsigned* w) {
#pragma unroll
    for (int cc = 0; cc < CH; ++cc) {
        uint4 u = *(const uint4*)(h + s * (CH * 128) + cc * 128 + q * 8);
        w[cc * 4 + 0] = u.x; w[cc * 4 + 1] = u.y;
        w[cc * 4 + 2] = u.z; w[cc * 4 + 3] = u.w;
    }
}

template <int CH>
__device__ __forceinline__ void accum_row(float a[][8], const unsigned* w) {
#pragma unroll
    for (int cc = 0; cc < CH; ++cc)
#pragma unroll
        for (int i = 0; i < 4; ++i) {
            a[cc][2 * i] += bf16lo_f(w[cc * 4 + i]);
            a[cc][2 * i + 1] += bf16hi_f(w[cc * 4 + i]);
        }
}

// ---------------- gather (bf16 normal-layout in) -> fragment-major bf16 A ----------------
// block = 16 nodes x 16 feature-chunk threads; 2-deep register-pipelined edge loop
// (standalone kernel, default VGPR budget -> no spill; ping-pong static buffers).
template <int K>
__global__ __launch_bounds__(256) void gather_frag(const unsigned short* __restrict__ h,
                                                   const int* __restrict__ rowptr,
                                                   const int* __restrict__ csr_src,
                                                   unsigned short* __restrict__ outA) {
    constexpr int CH = K / 128;
    const int nlow = threadIdx.x & 15;
    const int q = threadIdx.x >> 4;
    const int node = blockIdx.x * 16 + nlow;
    if (node >= M_NODES) return;

    float a[CH][8];
    {
        unsigned w[CH * 4];
        load_row<CH>(h, node, q, w);
#pragma unroll
        for (int cc = 0; cc < CH; ++cc)
#pragma unroll
            for (int i = 0; i < 4; ++i) {
                a[cc][2 * i] = bf16lo_f(w[cc * 4 + i]);
                a[cc][2 * i + 1] = bf16hi_f(w[cc * 4 + i]);
            }
    }

    const int beg = rowptr[node];
    const int n = rowptr[node + 1] - beg;
    unsigned bufA[CH * 4], bufB[CH * 4];
    if (n > 0) load_row<CH>(h, (long long)csr_src[beg], q, bufA);
    int i = 0;
    for (; i + 2 <= n; i += 2) {
        load_row<CH>(h, (long long)csr_src[beg + i + 1], q, bufB);
        accum_row<CH>(a, bufA);
        if (i + 2 < n) load_row<CH>(h, (long long)csr_src[beg + i + 2], q, bufA);
        accum_row<CH>(a, bufB);
    }
    if (i < n) accum_row<CH>(a, bufA);

#pragma unroll
    for (int cc = 0; cc < CH; ++cc) {
        uint4 o;
        o.x = (unsigned)bf16_rne(a[cc][0]) | ((unsigned)bf16_rne(a[cc][1]) << 16);
        o.y = (unsigned)bf16_rne(a[cc][2]) | ((unsigned)bf16_rne(a[cc][3]) << 16);
        o.z = (unsigned)bf16_rne(a[cc][4]) | ((unsigned)bf16_rne(a[cc][5]) << 16);
        o.w = (unsigned)bf16_rne(a[cc][6]) | ((unsigned)bf16_rne(a[cc][7]) << 16);
        long long off = ((long long)(node >> 4) * (K / 8) + cc * 16 + q) * 128 + nlow * 8;
        *(uint4*)(outA + off) = o;
    }
}

// ---------------- fused MLP, 512 threads / 8 waves, single-plane W ----------------
template <int K>
__global__ __launch_bounds__(512, 6) void fused_mlp(const unsigned short* __restrict__ A,
                                                    const unsigned short* __restrict__ W1,
                                                    const float* __restrict__ b1,
                                                    const unsigned short* __restrict__ W2,
                                                    const float* __restrict__ b2,
                                                    unsigned short* __restrict__ outH,
                                                    int M, float* __restrict__ bnsums) {
    __shared__ char lds_raw[32768];  // H tile: 64 rows x 256 cols bf16, XOR-swizzled

    const int tid = threadIdx.x;
    const int lane = tid & 63;
    const int wv = tid >> 6;
    const int gm = blockIdx.x * 64;
    const int l15 = lane & 15;
    const int kgrp = lane >> 4;
    const int rgrp = kgrp * 4;
    const int laneoff = kgrp * 128 + l15 * 8;

    floatx4 acc[4][2];
#pragma unroll
    for (int i = 0; i < 4; ++i)
#pragma unroll
        for (int j = 0; j < 2; ++j) acc[i][j] = (floatx4){0.f, 0.f, 0.f, 0.f};

    // ---------- stage 1: H = relu(A@W1+b1), A from global (frag-major) ----------
    long long aseg[4];
#pragma unroll
    for (int i = 0; i < 4; ++i) {
        int rt = (gm >> 4) + i;
        if (rt > M / 16 - 1) rt = M / 16 - 1;
        aseg[i] = (long long)rt * (K / 8) * 128;
    }

#pragma unroll
    for (int k0 = 0; k0 < K; k0 += 32) {
        short8v af[4], bh[2];
#pragma unroll
        for (int i = 0; i < 4; ++i)
            af[i] = *(const short8v*)(A + aseg[i] + k0 * 16 + laneoff);
#pragma unroll
        for (int j = 0; j < 2; ++j) {
            long long wb = (long long)((k0 >> 5) * 16 + wv * 2 + j) * 512 + laneoff;
            bh[j] = *(const short8v*)(W1 + wb);
        }
#pragma unroll
        for (int i = 0; i < 4; ++i)
#pragma unroll
            for (int j = 0; j < 2; ++j)
                acc[i][j] = __builtin_amdgcn_mfma_f32_16x16x32_bf16(af[i], bh[j], acc[i][j], 0, 0, 0);
    }

    // write relu'd bf16 H tile into swizzled LDS [64][256]
#pragma unroll
    for (int j = 0; j < 2; ++j) {
        int col = wv * 32 + j * 16 + l15;
        float bb = b1[col];
#pragma unroll
        for (int i = 0; i < 4; ++i) {
            int lrow = i * 16 + rgrp;
#pragma unroll
            for (int r = 0; r < 4; ++r) {
                int row = lrow + r;
                float v = fmaxf(acc[i][j][r] + bb, 0.f);
                int bo = (row * 512 + col * 2) ^ ((row & 7) << 4);
                *(unsigned short*)(lds_raw + bo) = bf16_rne(v);
            }
        }
    }
    __syncthreads();

    // ---------- stage 2: out = H@W2+b2, W2 single-plane ----------
#pragma unroll
    for (int i = 0; i < 4; ++i)
#pragma unroll
        for (int j = 0; j < 2; ++j) acc[i][j] = (floatx4){0.f, 0.f, 0.f, 0.f};

#pragma unroll
    for (int k0 = 0; k0 < HID_C; k0 += 32) {
        short8v af[4], bh[2];
#pragma unroll
        for (int i = 0; i < 4; ++i) {
            int row = i * 16 + l15;
            int bo = (row * 512 + (k0 + kgrp * 8) * 2) ^ ((row & 7) << 4);
            af[i] = *(const short8v*)(lds_raw + bo);
        }
#pragma unroll
        for (int j = 0; j < 2; ++j) {
            long long wb = (long long)((k0 >> 5) * 16 + wv * 2 + j) * 512 + laneoff;
            bh[j] = *(const short8v*)(W2 + wb);
        }
#pragma unroll
        for (int i = 0; i < 4; ++i)
#pragma unroll
            for (int j = 0; j < 2; ++j)
                acc[i][j] = __builtin_amdgcn_mfma_f32_16x16x32_bf16(af[i], bh[j], acc[i][j], 0, 0, 0);
    }

    // fused BN column sums (exact fp32 from accumulators)
#pragma unroll
    for (int j = 0; j < 2; ++j) {
        int col = wv * 32 + j * 16 + l15;
        float bb = b2[col];
        float s1 = 0.f, s2 = 0.f;
#pragma unroll
        for (int i = 0; i < 4; ++i) {
            int rowb = gm + i * 16 + rgrp;
#pragma unroll
            for (int r = 0; r < 4; ++r) {
                if (rowb + r < M) {
                    float v = acc[i][j][r] + bb;
                    s1 += v; s2 += v * v;
                }
            }
        }
        s1 += __shfl_xor(s1, 16); s1 += __shfl_xor(s1, 32);
        s2 += __shfl_xor(s2, 16); s2 += __shfl_xor(s2, 32);
        if ((lane >> 4) == 0) {
            atomicAdd(&bnsums[col], s1);
            atomicAdd(&bnsums[HID_C + col], s2);
        }
    }

    // coalesced bf16 epilogue via LDS (reuse lds_raw), 2 col-half phases
    unsigned short* stg = (unsigned short*)lds_raw;  // [64][132]
#pragma unroll
    for (int p = 0; p < 2; ++p) {
        __syncthreads();
        if ((wv >> 2) == p) {
#pragma unroll
            for (int j = 0; j < 2; ++j) {
                int col = wv * 32 + j * 16 + l15;
                int lcol = (wv & 3) * 32 + j * 16 + l15;
                float bb = b2[col];
#pragma unroll
                for (int i = 0; i < 4; ++i) {
                    int lrow = i * 16 + rgrp;
#pragma unroll
                    for (int r = 0; r < 4; ++r)
                        stg[(lrow + r) * 132 + lcol] = bf16_rne(acc[i][j][r] + bb);
                }
            }
        }
        __syncthreads();
#pragma unroll
        for (int it = 0; it < 4; ++it) {
            int idx = it * 512 + tid;
            int row = idx >> 5;
            int c4 = idx & 31;
            int grow = gm + row;
            if (grow < M)
                *(ushort4*)(outH + (long long)grow * HID_C + p * 128 + c4 * 4) =
                    *(const ushort4*)&stg[row * 132 + c4 * 4];
        }
    }
}

// ---------------- BatchNorm finalize ----------------
__global__ void bn_finalize(const float* __restrict__ sums, const float* __restrict__ gamma,
                            const float* __restrict__ beta, float* __restrict__ ss) {
    int f = threadIdx.x;
    float mean = sums[f] * (1.0f / M_NODES);
    float var = sums[HID_C + f] * (1.0f / M_NODES) - mean * mean;
    float sc = gamma[f] * rsqrtf(var + BN_EPS_C);
    ss[f] = sc;
    ss[HID_C + f] = beta[f] - mean * sc;
}

// ---------------- pooling (bf16 in, fused BN+relu) ----------------
#define POOL_BLOCKS 4096
#define POOL_RPB 25
__global__ void pool_bn(const unsigned short* __restrict__ h, const float* __restrict__ ss,
                        const int* __restrict__ batch, float* __restrict__ sums, int M) {
    int f = threadIdx.x;
    float sc = ss[f], sh = ss[HID_C + f];
    int r0 = blockIdx.x * POOL_RPB;
    if (r0 >= M) return;
    int r1 = r0 + POOL_RPB;
    if (r1 > M) r1 = M;
    int cur = batch[r0];
    float acc = 0.f;
    for (int r = r0; r < r1; ++r) {
        int g = batch[r];
        if (g != cur) {
            atomicAdd(&sums[(long long)cur * HID_C + f], acc);
            acc = 0.f;
            cur = g;
        }
        float v = bf16_to_f(h[(long long)r * HID_C + f]);
        acc += fmaxf(fmaf(v, sc, sh), 0.f);
    }
    atomicAdd(&sums[(long long)cur * HID_C + f], acc);
}

__device__ __forceinline__ int lower_bound_i(const int* a, int n, int v) {
    int lo = 0, hi = n;
    while (lo < hi) {
        int mid = (lo + hi) >> 1;
        if (a[mid] < v) lo = mid + 1;
        else hi = mid;
    }
    return lo;
}

__global__ void pool_finalize(const float* __restrict__ sums, const int* __restrict__ batch,
                              float* __restrict__ out) {
    int g = blockIdx.x, f = threadIdx.x;
    int lb = lower_bound_i(batch, M_NODES, g);
    int ub = lower_bound_i(batch, M_NODES, g + 1);
    float cnt = (float)(ub - lb);
    out[(long long)g * HID_C + f] = sums[(long long)g * HID_C + f] / fmaxf(cnt, 1.0f);
}

// ---------------- launch ----------------
extern "C" void kernel_launch(void* const* d_in, const int* in_sizes, int n_in,
                              void* d_out, int out_size, void* d_ws, size_t ws_size,
                              hipStream_t stream) {
    const float* x = (const float*)d_in[0];
    const int* ei = (const int*)d_in[1];
    const int* esrc = ei;
    const int* edst = ei + N_EDGES_C;
    const int* batch = (const int*)d_in[2];
    const float* W1_0 = (const float*)d_in[3];
    const float* b1_0 = (const float*)d_in[4];
    const float* W2_0 = (const float*)d_in[5];
    const float* b2_0 = (const float*)d_in[6];
    const float* g0 = (const float*)d_in[7];
    const float* be0 = (const float*)d_in[8];
    const float* W1_1 = (const float*)d_in[9];
    const float* b1_1 = (const float*)d_in[10];
    const float* W2_1 = (const float*)d_in[11];
    const float* b2_1 = (const float*)d_in[12];
    const float* g1 = (const float*)d_in[13];
    const float* be1 = (const float*)d_in[14];
    float* out = (float*)d_out;

    const long long NF = (long long)M_NODES * HID_C;
    const long long NI = (long long)M_NODES * IN_DIM_C;
    unsigned short* U = (unsigned short*)d_ws;
    unsigned short* X16 = U;           // NI  (bf16 x)          [dead after L0 gather]
    unsigned short* A0 = U + NI;       // NI  (frag-major)      [dead after L0 mlp]
    unsigned short* P1 = U;            // NF  (aliases X16+A0; written by bnrelu)
    unsigned short* Hb0 = U + 2 * NI;  // NF  (pre-BN out L0)
    unsigned short* A1 = Hb0 + NF;     // NF  (frag-major)
    unsigned short* Hb1 = A1 + NF;     // NF  (pre-BN out L1)
    float* fbase = (float*)(Hb1 + NF);
    float* bns = fbase;
    float* ss0 = bns + 2 * HID_C;
    float* ss1 = ss0 + 2 * HID_C;
    float* psum = ss1 + 2 * HID_C;
    int* counts = (int*)(psum + N_GRAPHS_C * HID_C);
    int* partials = counts + 100352;
    int* rowptr = partials + 512;
    int* csr_src = rowptr + 100004;
    unsigned short* wp = (unsigned short*)(csr_src + N_EDGES_C);
    unsigned short* w1A = wp;                      // 128*256 single-plane
    unsigned short* w2B = w1A + IN_DIM_C * HID_C;  // 256*256 single-plane
    unsigned short* w1C = w2B + HID_C * HID_C;
    unsigned short* w2D = w1C + HID_C * HID_C;

    dim3 blk(256);
    dim3 fgrid((M_NODES + 63) / 64);
    dim3 ggrid((M_NODES + 15) / 16);

    // ---- W packs (fragment-major, single-plane) ----
    wpack<IN_DIM_C><<<(IN_DIM_C * HID_C + 255) / 256, blk, 0, stream>>>(W1_0, w1A);
    wpack<HID_C><<<(HID_C * HID_C + 255) / 256, blk, 0, stream>>>(W2_0, w2B);
    wpack<HID_C><<<(HID_C * HID_C + 255) / 256, blk, 0, stream>>>(W1_1, w1C);
    wpack<HID_C><<<(HID_C * HID_C + 255) / 256, blk, 0, stream>>>(W2_1, w2D);

    // ---- CSR build ----
    zero_i<<<(M_NODES + 255) / 256, blk, 0, stream>>>(counts, M_NODES);
    csr_count<<<(N_EDGES_C + 255) / 256, blk, 0, stream>>>(edst, counts);
    block_scan<<<392, blk, 0, stream>>>(counts, rowptr, partials);
    scan_partials<<<1, 512, 0, stream>>>(partials, 392);
    add_offsets<<<392, blk, 0, stream>>>(rowptr, partials);
    copy_i<<<(M_NODES + 255) / 256, blk, 0, stream>>>(rowptr, counts, M_NODES);
    csr_fill<<<(N_EDGES_C + 255) / 256, blk, 0, stream>>>(esrc, edst, counts, csr_src);

    // ---- x -> bf16 ----
    f2b<<<(int)((NI / 4 + 255) / 256), blk, 0, stream>>>((const float4*)x, (ushort4*)X16,
                                                         (int)(NI / 4));

    // ---- Layer 0 ----
    gather_frag<IN_DIM_C><<<ggrid, blk, 0, stream>>>(X16, rowptr, csr_src, A0);
    zero_f<<<2, blk, 0, stream>>>(bns, 2 * HID_C);
    fused_mlp<IN_DIM_C><<<fgrid, dim3(512), 0, stream>>>(A0, w1A, b1_0, w2B, b2_0,
                                                         Hb0, M_NODES, bns);
    bn_finalize<<<1, blk, 0, stream>>>(bns, g0, be0, ss0);

    // ---- P1 = relu(BN(Hb0))  (aliases dead X16+A0 region) ----
    bnrelu<<<(int)((NF / 8 + 255) / 256), blk, 0, stream>>>(Hb0, ss0, P1, (int)(NF / 8));

    // ---- Layer 1 ----
    gather_frag<HID_C><<<ggrid, blk, 0, stream>>>(P1, rowptr, csr_src, A1);
    zero_f<<<2, blk, 0, stream>>>(bns, 2 * HID_C);
    fused_mlp<HID_C><<<fgrid, dim3(512), 0, stream>>>(A1, w1C, b1_1, w2D, b2_1,
                                                      Hb1, M_NODES, bns);
    bn_finalize<<<1, blk, 0, stream>>>(bns, g1, be1, ss1);

    // ---- Pool (fused BN+relu) ----
    zero_f<<<(N_GRAPHS_C * HID_C + 255) / 256, blk, 0, stream>>>(psum, N_GRAPHS_C * HID_C);
    pool_bn<<<POOL_BLOCKS, blk, 0, stream>>>(Hb1, ss1, batch, psum, M_NODES);
    pool_finalize<<<256, blk, 0, stream>>>(psum, batch, out);
}